// Round 10
// baseline (291.062 us; speedup 1.0000x reference)
//
#include <hip/hip_runtime.h>
#include <hip/hip_bf16.h>
#include <cstdint>

typedef unsigned short u16;
typedef unsigned int   u32;
typedef __attribute__((ext_vector_type(8))) short short8;   // 8 bf16 (4 VGPRs) MFMA A/B frag
typedef __attribute__((ext_vector_type(4))) float f32x4;    // MFMA C/D frag / float4 load
typedef __attribute__((ext_vector_type(4))) u32  u32x4;     // 16B load/store
typedef __attribute__((ext_vector_type(2))) u32  u32x2;

#define DEV static __device__ __forceinline__

DEV float bf2f(u16 u){ u32 t = ((u32)u) << 16; float f; __builtin_memcpy(&f, &t, 4); return f; }
DEV u16 f2bf(float f){ u32 t; __builtin_memcpy(&t, &f, 4); return (u16)((t + 0x7fffu + ((t >> 16) & 1u)) >> 16); }

#if __has_builtin(__builtin_amdgcn_exp2f)
DEV float fast_exp2(float x){ return __builtin_amdgcn_exp2f(x); }
#else
DEV float fast_exp2(float x){ return exp2f(x); }
#endif

// pack hi16(x) | hi16(y)<<16  (truncation; P in [0,1])
DEV u32 pack_trunc(float x, float y){
    u32 tx, ty; __builtin_memcpy(&tx, &x, 4); __builtin_memcpy(&ty, &y, 4);
#if __has_builtin(__builtin_amdgcn_perm)
    return __builtin_amdgcn_perm(ty, tx, 0x07060302);   // bytes: [x2,x3,y2,y3]
#else
    return (tx >> 16) | (ty & 0xFFFF0000u);
#endif
}

// async global->LDS, 16B per lane. LDS dst must be wave-uniform; HW writes dst + lane*16.
DEV void gload_lds16(const void* g, void* l) {
    __builtin_amdgcn_global_load_lds((__attribute__((address_space(1))) void*)(g),
                                     (__attribute__((address_space(3))) void*)(l), 16, 0, 0);
}

// In-register quad exchange replacing the Ps LDS round-trip. (Verified in r9 bench.)
DEV short8 xchg_quads(u32 a0, u32 a1, u32 b0, u32 b1)
{
    u32 x0 = a0, y0 = b0;
    asm("v_permlane32_swap_b32 %0, %1" : "+v"(x0), "+v"(y0));
    asm("v_permlane16_swap_b32 %0, %1" : "+v"(x0), "+v"(y0));
    u32 x1 = a1, y1 = b1;
    asm("v_permlane32_swap_b32 %0, %1" : "+v"(x1), "+v"(y1));
    asm("v_permlane16_swap_b32 %0, %1" : "+v"(x1), "+v"(y1));
    union { u32 w[4]; short8 v; } u;
    u.w[0] = x0; u.w[1] = x1; u.w[2] = y0; u.w[3] = y1;
    return u.v;
}

// mode heuristic: exponent-field sanity of u16 words at even indices of x (4 KB).
DEV bool block_detect_f32(const u16* __restrict__ x, int tid, int* red)
{
    int crazy = 0;
    for (int i = tid; i < 1024; i += 256) {
        u16 v = x[2 * i];
        int e = (v >> 7) & 0xFF;
        if (e >= 0x9F || (e > 0 && e <= 0x5F)) crazy++;
    }
    #pragma unroll
    for (int off = 1; off < 64; off <<= 1) crazy += __shfl_xor(crazy, off, 64);
    if ((tid & 63) == 0) red[tid >> 6] = crazy;
    __syncthreads();
    return (red[0] + red[1] + red[2] + red[3] > 128);
}

// ---------------------------------------------------------------- fused front-end: convert + LN
// r16: single dispatch replacing convert_params + ln_kernel (5 -> 4 kernels).
//   blocks [0,2048):    weight convert, 8 elems/thread (r9-verified path)
//   blocks [2048,2069): small-vector convert (r9-verified path)
//   blocks [2069,4117): LayerNorm, 1 wave/row — norm_w/b read RAW from inputs (inline convert),
//                       removing the dependency on the convert blocks.
// Every block runs the 4 KB mode probe locally (L2-broadcast); block 0 publishes *mode for
// the downstream gemm_o epilogue.
struct SrcPtrs { const void* p[13]; };

__global__ __launch_bounds__(256) void prep(SrcPtrs sp, const u16* __restrict__ x,
                                            u16* __restrict__ ws, int* __restrict__ mode,
                                            u16* __restrict__ xn)
{
    __shared__ int red[4];
    const int tid = threadIdx.x;
    const bool f = block_detect_f32(x, tid, red);
    const int bid = blockIdx.x;
    if (bid == 0 && tid == 0) *mode = f ? 1 : 0;

    u16* cW = ws + 33554432;
    u16* cV = ws + 37748736;
    if (bid < 2048) {
        const int i = (bid * 256 + tid) * 8;                   // 0..4194296, 16B-aligned
        const int t = i >> 20, off = i & 1048575;
        const void* src = (t == 0) ? sp.p[6] : (t == 1) ? sp.p[8] : (t == 2) ? sp.p[10] : sp.p[12];
        if (f) {
            f32x4 a = *(const f32x4*)((const float*)src + off);
            f32x4 c = *(const f32x4*)((const float*)src + off + 4);
            u32x4 o;
            o.x = (u32)f2bf(a[0]) | ((u32)f2bf(a[1]) << 16);
            o.y = (u32)f2bf(a[2]) | ((u32)f2bf(a[3]) << 16);
            o.z = (u32)f2bf(c[0]) | ((u32)f2bf(c[1]) << 16);
            o.w = (u32)f2bf(c[2]) | ((u32)f2bf(c[3]) << 16);
            *(u32x4*)(cW + i) = o;
        } else {
            *(u32x4*)(cW + i) = *(const u32x4*)((const u16*)src + off);
        }
    } else if (bid < 2069) {
        const int j = (bid - 2048) * 256 + tid;
        if (j >= 5376) return;
        const void* src; int off;
        if      (j < 1024) { src = sp.p[0];  off = j; }
        else if (j < 2048) { src = sp.p[1];  off = j - 1024; }
        else if (j < 3072) { src = sp.p[7];  off = j - 2048; }
        else if (j < 4096) { src = sp.p[9];  off = j - 3072; }
        else if (j < 5120) { src = sp.p[11]; off = j - 4096; }
        else { int m = j - 5120; src = sp.p[2 + (m >> 6)]; off = m & 63; }
        cV[j] = f ? f2bf(((const float*)src)[off]) : ((const u16*)src)[off];
    } else {
        const int row  = (bid - 2069) * 4 + (tid >> 6);
        const int lane = tid & 63;
        const int base = lane * 16;

        float v[16], lw[16], lb[16];
        if (f) {
            const float* xr = (const float*)x + (size_t)row * 1024 + base;
            const float* wr = (const float*)sp.p[0] + base;
            const float* br = (const float*)sp.p[1] + base;
            #pragma unroll
            for (int c = 0; c < 4; c++) {
                f32x4 r4 = *(const f32x4*)(xr + c * 4);
                f32x4 w4 = *(const f32x4*)(wr + c * 4);
                f32x4 b4 = *(const f32x4*)(br + c * 4);
                #pragma unroll
                for (int q = 0; q < 4; q++) { v[c*4+q] = r4[q]; lw[c*4+q] = w4[q]; lb[c*4+q] = b4[q]; }
            }
        } else {
            const u16* xr = (const u16*)x + (size_t)row * 1024 + base;
            const u16* wr = (const u16*)sp.p[0] + base;
            const u16* br = (const u16*)sp.p[1] + base;
            #pragma unroll
            for (int c = 0; c < 2; c++) {
                u32x4 r4 = *(const u32x4*)(xr + c * 8);
                u32x4 w4 = *(const u32x4*)(wr + c * 8);
                u32x4 b4 = *(const u32x4*)(br + c * 8);
                #pragma unroll
                for (int q = 0; q < 4; q++) {
                    u32 xd = (q == 0) ? r4.x : (q == 1) ? r4.y : (q == 2) ? r4.z : r4.w;
                    u32 wd = (q == 0) ? w4.x : (q == 1) ? w4.y : (q == 2) ? w4.z : w4.w;
                    u32 bd = (q == 0) ? b4.x : (q == 1) ? b4.y : (q == 2) ? b4.z : b4.w;
                    v[c*8+q*2]    = bf2f((u16)(xd & 0xffff)); v[c*8+q*2+1]  = bf2f((u16)(xd >> 16));
                    lw[c*8+q*2]   = bf2f((u16)(wd & 0xffff)); lw[c*8+q*2+1] = bf2f((u16)(wd >> 16));
                    lb[c*8+q*2]   = bf2f((u16)(bd & 0xffff)); lb[c*8+q*2+1] = bf2f((u16)(bd >> 16));
                }
            }
        }
        float s = 0.0f, sq = 0.0f;
        #pragma unroll
        for (int i = 0; i < 16; i++) { s += v[i]; sq += v[i] * v[i]; }
        #pragma unroll
        for (int off = 1; off < 64; off <<= 1) {
            s  += __shfl_xor(s,  off, 64);
            sq += __shfl_xor(sq, off, 64);
        }
        const float mean = s * (1.0f / 1024.0f);
        const float var  = sq * (1.0f / 1024.0f) - mean * mean;
        const float rs   = rsqrtf(var + 1e-5f);

        #pragma unroll
        for (int c = 0; c < 2; c++) {
            u32x4 o;
            #pragma unroll
            for (int q = 0; q < 4; q++) {
                float y0 = (v[c*8+q*2]   - mean) * rs * lw[c*8+q*2]   + lb[c*8+q*2];
                float y1 = (v[c*8+q*2+1] - mean) * rs * lw[c*8+q*2+1] + lb[c*8+q*2+1];
                u32 pk = (u32)f2bf(y0) | ((u32)f2bf(y1) << 16);
                if (q == 0) o.x = pk; else if (q == 1) o.y = pk; else if (q == 2) o.z = pk; else o.w = pk;
            }
            *(u32x4*)(xn + (size_t)row * 1024 + base + c * 8) = o;
        }
    }
}

// ---------------------------------------------------------------- m97-class GEMM + XOR bank swizzle
// C = A[8192][1024] @ W[N][1024]^T. 128x128 tile, BK=64, global_load_lds(16B) staging.
// (Proven r3/r5 structure.)
__global__ __launch_bounds__(256, 4) void gemm128(const u16* __restrict__ A,
                                                  const u16* __restrict__ W,
                                                  const u16* __restrict__ bias,
                                                  void* __restrict__ out0,
                                                  u16* __restrict__ vt,
                                                  const u16* __restrict__ qnw, const u16* __restrict__ qnb,
                                                  const u16* __restrict__ knw, const u16* __restrict__ knb,
                                                  const int* __restrict__ mode,
                                                  int epi, int N)
{
    __shared__ u16 As[128 * 64];
    __shared__ u16 Bs[128 * 64];
    const int tid = threadIdx.x;
    const int m0 = blockIdx.x * 128, n0 = blockIdx.y * 128;
    const int wv = tid >> 6, lane = tid & 63, quad = lane >> 4, l16 = lane & 15;
    const int wm = wv & 1, wn = wv >> 1;

    f32x4 acc[4][4] = {};

    const int srow = tid >> 3;
    const int scol = (((tid & 7) - (srow & 7)) & 7) * 8;
    const u16* Ap = A + (size_t)(m0 + srow) * 1024 + scol;
    const u16* Wp = W + (size_t)(n0 + srow) * 1024 + scol;

    const int swz0 = ((quad     + l16) & 7) * 8;
    const int swz1 = ((quad + 4 + l16) & 7) * 8;

    for (int k0 = 0; k0 < 1024; k0 += 64) {
        #pragma unroll
        for (int i = 0; i < 4; i++)
            gload_lds16(Ap + k0 + (size_t)i * 32 * 1024, &As[i * 2048 + wv * 512]);
        #pragma unroll
        for (int i = 0; i < 4; i++)
            gload_lds16(Wp + k0 + (size_t)i * 32 * 1024, &Bs[i * 2048 + wv * 512]);
        __syncthreads();
        #pragma unroll
        for (int kh = 0; kh < 2; kh++) {
            const int sw = kh ? swz1 : swz0;
            short8 af[4], bf[4];
            #pragma unroll
            for (int mi = 0; mi < 4; mi++)
                af[mi] = *(const short8*)&As[(wm * 64 + mi * 16 + l16) * 64 + sw];
            #pragma unroll
            for (int ni = 0; ni < 4; ni++)
                bf[ni] = *(const short8*)&Bs[(wn * 64 + ni * 16 + l16) * 64 + sw];
            #pragma unroll
            for (int mi = 0; mi < 4; mi++)
                #pragma unroll
                for (int ni = 0; ni < 4; ni++)
                    acc[mi][ni] = __builtin_amdgcn_mfma_f32_16x16x32_bf16(af[mi], bf[ni], acc[mi][ni], 0, 0, 0);
        }
        __syncthreads();
    }

    if (epi == 1) {
        const int colbase = n0 + wn * 64;
        if (colbase < 2048) {
            const bool isK = colbase >= 1024;
            const u16* lw = isK ? knw : qnw;
            const u16* lb = isK ? knb : qnb;
            const float scale = isK ? 1.0f : 0.18033688011112042f;   // 0.125 * log2(e)
            float lnw[4], lnb2[4], bv[4];
            #pragma unroll
            for (int ni = 0; ni < 4; ni++) {
                const int dh = ni * 16 + l16;
                lnw[ni] = bf2f(lw[dh]); lnb2[ni] = bf2f(lb[dh]); bv[ni] = bf2f(bias[colbase + dh]);
            }
            u16* qk = (u16*)out0;
            #pragma unroll
            for (int mi = 0; mi < 4; mi++) {
                #pragma unroll
                for (int r = 0; r < 4; r++) {
                    float v[4];
                    float s = 0.0f, sq = 0.0f;
                    #pragma unroll
                    for (int ni = 0; ni < 4; ni++) {
                        v[ni] = acc[mi][ni][r] + bv[ni];
                        s += v[ni]; sq += v[ni] * v[ni];
                    }
                    #pragma unroll
                    for (int off = 1; off < 16; off <<= 1) {
                        s  += __shfl_xor(s,  off, 64);
                        sq += __shfl_xor(sq, off, 64);
                    }
                    const float mean = s * (1.0f / 64.0f);
                    const float var  = sq * (1.0f / 64.0f) - mean * mean;
                    const float rs   = rsqrtf(var + 1e-5f);
                    const int row = m0 + wm * 64 + mi * 16 + quad * 4 + r;
                    #pragma unroll
                    for (int ni = 0; ni < 4; ni++)
                        qk[(size_t)row * 2048 + colbase + ni * 16 + l16] =
                            f2bf(((v[ni] - mean) * rs * lnw[ni] + lnb2[ni]) * scale);
                }
            }
        } else {
            const int cp0 = colbase - 2048;
            #pragma unroll
            for (int ni = 0; ni < 4; ni++) {
                const int cp = cp0 + ni * 16 + l16;            // 0..1023
                const int h = cp >> 6, dh = cp & 63;
                const float bvv = bf2f(bias[2048 + cp]);
                #pragma unroll
                for (int mi = 0; mi < 4; mi++) {
                    const int row0 = m0 + wm * 64 + mi * 16 + quad * 4;
                    const int bb = row0 >> 11, nn = row0 & 2047;
                    u32x2 pk;
                    pk.x = (u32)f2bf(acc[mi][ni][0] + bvv) | ((u32)f2bf(acc[mi][ni][1] + bvv) << 16);
                    pk.y = (u32)f2bf(acc[mi][ni][2] + bvv) | ((u32)f2bf(acc[mi][ni][3] + bvv) << 16);
                    *(u32x2*)&vt[(size_t)(((bb * 16 + h) * 64) + dh) * 2048 + nn] = pk;
                }
            }
        }
    } else {
        const bool f32o = (*mode != 0);
        #pragma unroll
        for (int ni = 0; ni < 4; ni++) {
            const int col = n0 + wn * 64 + ni * 16 + l16;
            #pragma unroll
            for (int mi = 0; mi < 4; mi++) {
                const int row0 = m0 + wm * 64 + mi * 16 + quad * 4;
                #pragma unroll
                for (int r = 0; r < 4; r++) {
                    const float val = acc[mi][ni][r];
                    if (f32o) ((float*)out0)[(size_t)(row0 + r) * 1024 + col] = val;
                    else      ((u16*)out0)[(size_t)(row0 + r) * 1024 + col]  = f2bf(val);
                }
            }
        }
    }
}

// ---------------------------------------------------------------- O-projection GEMM, BM=64 x BN=128
// r13: grid (128,8) = 1024 blocks = 4 blocks/CU. (Verified r7.)
__global__ __launch_bounds__(256, 4) void gemm_o(const u16* __restrict__ A,
                                                 const u16* __restrict__ W,
                                                 void* __restrict__ out0,
                                                 const int* __restrict__ mode)
{
    __shared__ u16 As[64 * 64];
    __shared__ u16 Bs[128 * 64];
    const int tid = threadIdx.x;
    const int m0 = blockIdx.x * 64, n0 = blockIdx.y * 128;
    const int wv = tid >> 6, lane = tid & 63, quad = lane >> 4, l16 = lane & 15;

    f32x4 acc[4][2] = {};

    const int srow = tid >> 3;                               // 0..31 (wave wv covers rows wv*8..+7)
    const int scol = (((tid & 7) - (srow & 7)) & 7) * 8;
    const u16* Ap = A + (size_t)(m0 + srow) * 1024 + scol;
    const u16* Wp = W + (size_t)(n0 + srow) * 1024 + scol;

    const int swz0 = ((quad     + l16) & 7) * 8;
    const int swz1 = ((quad + 4 + l16) & 7) * 8;

    for (int k0 = 0; k0 < 1024; k0 += 64) {
        #pragma unroll
        for (int i = 0; i < 2; i++)
            gload_lds16(Ap + k0 + (size_t)i * 32 * 1024, &As[i * 2048 + wv * 512]);
        #pragma unroll
        for (int i = 0; i < 4; i++)
            gload_lds16(Wp + k0 + (size_t)i * 32 * 1024, &Bs[i * 2048 + wv * 512]);
        __syncthreads();
        #pragma unroll
        for (int kh = 0; kh < 2; kh++) {
            const int sw = kh ? swz1 : swz0;
            short8 af[4], bf[2];
            #pragma unroll
            for (int mi = 0; mi < 4; mi++)
                af[mi] = *(const short8*)&As[(mi * 16 + l16) * 64 + sw];
            #pragma unroll
            for (int ni = 0; ni < 2; ni++)
                bf[ni] = *(const short8*)&Bs[(wv * 32 + ni * 16 + l16) * 64 + sw];
            #pragma unroll
            for (int mi = 0; mi < 4; mi++)
                #pragma unroll
                for (int ni = 0; ni < 2; ni++)
                    acc[mi][ni] = __builtin_amdgcn_mfma_f32_16x16x32_bf16(af[mi], bf[ni], acc[mi][ni], 0, 0, 0);
        }
        __syncthreads();
    }

    const bool f32o = (*mode != 0);
    #pragma unroll
    for (int ni = 0; ni < 2; ni++) {
        const int col = n0 + wv * 32 + ni * 16 + l16;
        #pragma unroll
        for (int mi = 0; mi < 4; mi++) {
            const int row0 = m0 + mi * 16 + quad * 4;
            #pragma unroll
            for (int r = 0; r < 4; r++) {
                const float val = acc[mi][ni][r];
                if (f32o) ((float*)out0)[(size_t)(row0 + r) * 1024 + col] = val;
                else      ((u16*)out0)[(size_t)(row0 + r) * 1024 + col]  = f2bf(val);
            }
        }
    }
}

// ---------------------------------------------------------------- flash attention, O^T, fixed-max softmax
// EXACT r9-passing attn: in-register P exchange, K/V double-buffer 2-phase, XCD-aware remap.
#define ATTN_STAGE(BUF) do { \
    gload_lds16(kp0, &Ks[BUF][wv * 1024]); \
    gload_lds16(kp1, &Ks[BUF][wv * 1024 + 512]); \
    gload_lds16(vp0, &Vs[BUF][wv * 1024]); \
    gload_lds16(vp1, &Vs[BUF][wv * 1024 + 512]); \
    kp0 += 64 * 2048; kp1 += 64 * 2048; vp0 += 64; vp1 += 64; } while (0)

#define ATTN_BODY(CUR, NXT, J0, DO_STAGE, DO_BAR) do { \
    if (DO_STAGE) ATTN_STAGE(NXT); \
    f32x4 sfr[2][4]; \
    _Pragma("unroll") \
    for (int sub = 0; sub < 4; sub++) { \
        short8 kf0 = *(const short8*)&Ks[CUR][krow + swz0 + sub * 1024]; \
        short8 kf1 = *(const short8*)&Ks[CUR][krow + swz1 + sub * 1024]; \
        f32x4 mrow = *(const f32x4*)&maskf[(J0) + sub * 16 + quad * 4]; \
        _Pragma("unroll") \
        for (int g = 0; g < 2; g++) { \
            f32x4 sz = mrow; \
            sz = __builtin_amdgcn_mfma_f32_16x16x32_bf16(kf0, qf[g][0], sz, 0, 0, 0); \
            sz = __builtin_amdgcn_mfma_f32_16x16x32_bf16(kf1, qf[g][1], sz, 0, 0, 0); \
            sfr[g][sub] = sz; \
        } \
    } \
    short8 pf[2][2]; \
    _Pragma("unroll") \
    for (int g = 0; g < 2; g++) { \
        float lp = 0.0f; \
        _Pragma("unroll") \
        for (int sub = 0; sub < 4; sub++) \
            _Pragma("unroll") \
            for (int r = 0; r < 4; r++) { \
                float e = fast_exp2(sfr[g][sub][r]); \
                sfr[g][sub][r] = e; lp += e; \
            } \
        l_lane[g] += lp; \
        u32 W00 = pack_trunc(sfr[g][0][0], sfr[g][0][1]); \
        u32 W01 = pack_trunc(sfr[g][0][2], sfr[g][0][3]); \
        u32 W10 = pack_trunc(sfr[g][1][0], sfr[g][1][1]); \
        u32 W11 = pack_trunc(sfr[g][1][2], sfr[g][1][3]); \
        u32 W20 = pack_trunc(sfr[g][2][0], sfr[g][2][1]); \
        u32 W21 = pack_trunc(sfr[g][2][2], sfr[g][2][3]); \
        u32 W30 = pack_trunc(sfr[g][3][0], sfr[g][3][1]); \
        u32 W31 = pack_trunc(sfr[g][3][2], sfr[g][3][3]); \
        pf[g][0] = xchg_quads(W00, W01, W10, W11); \
        pf[g][1] = xchg_quads(W20, W21, W30, W31); \
    } \
    _Pragma("unroll") \
    for (int dht = 0; dht < 4; dht++) { \
        short8 vf0 = *(const short8*)&Vs[CUR][krow + swz0 + dht * 1024]; \
        short8 vf1 = *(const short8*)&Vs[CUR][krow + swz1 + dht * 1024]; \
        _Pragma("unroll") \
        for (int g = 0; g < 2; g++) { \
            O[g][dht] = __builtin_amdgcn_mfma_f32_16x16x32_bf16(vf0, pf[g][0], O[g][dht], 0, 0, 0); \
            O[g][dht] = __builtin_amdgcn_mfma_f32_16x16x32_bf16(vf1, pf[g][1], O[g][dht], 0, 0, 0); \
        } \
    } \
    if (DO_BAR) { \
        asm volatile("s_waitcnt vmcnt(0)" ::: "memory"); \
        __builtin_amdgcn_s_barrier(); \
    } } while (0)

__global__ __launch_bounds__(256, 4) void attn(const u16* __restrict__ qk, const u16* __restrict__ vt,
                                               const int* __restrict__ mask, u16* __restrict__ ctx)
{
    __shared__ __align__(16) float maskf[2048];     // 8 KB
    __shared__ __align__(16) u16 Ks[2][64 * 64];    // 16 KB [buf][j][dh] swizzled
    __shared__ __align__(16) u16 Vs[2][64 * 64];    // 16 KB [buf][dh][j] swizzled

    // XCD-aware remap: all 16 i-blocks of one (b,h) on one XCD (dispatch round-robin lin%8).
    const int lin = blockIdx.x;
    const int xcd = lin & 7, slot = lin >> 3;       // slot 0..127
    const int bh = (slot >> 4) * 8 + xcd;           // 0..63
    const int i0 = (slot & 15) * 128;
    const int b = bh >> 4, h = bh & 15;
    const int tid = threadIdx.x, wv = tid >> 6, lane = tid & 63, quad = lane >> 4, l16 = lane & 15;

    for (int idx = tid; idx < 2048; idx += 256)
        maskf[idx] = mask[b * 2048 + idx] ? -12.0f : -1e9f;

    const u16* qbase = qk + (size_t)(b * 2048) * 2048 + h * 64;
    const u16* kbase = qbase + 1024;
    const u16* vbase = vt + (size_t)(bh * 64) * 2048;   // rows = dh, cols = n

    short8 qf[2][2];
    #pragma unroll
    for (int g = 0; g < 2; g++) {
        const int iw = i0 + wv * 32 + g * 16 + l16;
        qf[g][0] = *(const short8*)(qbase + (size_t)iw * 2048 + quad * 8);
        qf[g][1] = *(const short8*)(qbase + (size_t)iw * 2048 + 32 + quad * 8);
    }

    f32x4 O[2][4] = {};
    float l_lane[2] = {0.0f, 0.0f};

    const int sr = lane >> 3, ss = lane & 7;
    const int sck = ((ss - sr) & 7) * 8;
    const u16* kp0 = kbase + (size_t)(wv * 16 +      sr) * 2048 + sck;
    const u16* kp1 = kbase + (size_t)(wv * 16 + 8  + sr) * 2048 + sck;
    const u16* vp0 = vbase + (size_t)(wv * 16 +      sr) * 2048 + sck;
    const u16* vp1 = vbase + (size_t)(wv * 16 + 8  + sr) * 2048 + sck;

    const int swz0 = ((quad     + l16) & 7) * 8;
    const int swz1 = ((quad + 4 + l16) & 7) * 8;
    const int krow = l16 * 64;

    ATTN_STAGE(0);
    asm volatile("s_waitcnt vmcnt(0) lgkmcnt(0)" ::: "memory");
    __builtin_amdgcn_s_barrier();

    for (int j0 = 0; j0 < 2048; j0 += 128) {
        ATTN_BODY(0, 1, j0, true, true);
        const bool more = (j0 + 128) < 2048;
        ATTN_BODY(1, 0, j0 + 64, more, more);
    }

    #pragma unroll
    for (int g = 0; g < 2; g++) {
        float l = l_lane[g];
        l += __shfl_xor(l, 16, 64);
        l += __shfl_xor(l, 32, 64);
        const float inv = l > 0.0f ? 1.0f / l : 0.0f;
        const int iw = i0 + wv * 32 + g * 16 + l16;
        u16* cb = ctx + (size_t)(b * 2048 + iw) * 1024 + h * 64;
        #pragma unroll
        for (int dht = 0; dht < 4; dht++) {
            u32x2 pk;
            pk.x = (u32)f2bf(O[g][dht][0] * inv) | ((u32)f2bf(O[g][dht][1] * inv) << 16);
            pk.y = (u32)f2bf(O[g][dht][2] * inv) | ((u32)f2bf(O[g][dht][3] * inv) << 16);
            *(u32x2*)(cb + dht * 16 + quad * 4) = pk;
        }
    }
}

// ----------------------------------------------------------------
extern "C" void kernel_launch(void* const* d_in, const int* in_sizes, int n_in,
                              void* d_out, int out_size, void* d_ws, size_t ws_size,
                              hipStream_t stream)
{
    const int* mask = (const int*)d_in[1];

    u16* ws = (u16*)d_ws;
    u16* xn  = ws;                      // [0, 8388608)
    u16* qkb = ws + 8388608;            // [8388608, 25165824)  [8192][2048]
    u16* vtb = ws + 25165824;           // [25165824, 33554432) [4][16][64][2048]
    u16* ctx = xn;                      // xn dead after QKV GEMM; reuse
    u16* cW  = ws + 33554432;           // Wq|Wk|Wv|Wo
    u16* cV  = ws + 37748736;           // vectors (5376)
    int* mode = (int*)(ws + 37754176);

    SrcPtrs sp;
    for (int i = 0; i < 13; i++) sp.p[i] = d_in[i + 2];

    // fused convert + LN (one dispatch; LN reads norm params raw)
    prep<<<dim3(4117), dim3(256), 0, stream>>>(sp, (const u16*)d_in[0], ws, mode, xn);

    // fused QKV + head-LN: N=3072, stacked W = cW (Wq|Wk|Wv), stacked bias = cV+2048
    gemm128<<<dim3(64, 24), dim3(256), 0, stream>>>(xn, cW, cV + 2048, qkb, vtb,
                                                    cV + 5120, cV + 5184, cV + 5248, cV + 5312,
                                                    mode, 1, 3072);

    attn<<<dim3(1024), dim3(256), 0, stream>>>(qkb, vtb, mask, ctx);

    gemm_o<<<dim3(128, 8), dim3(256), 0, stream>>>(ctx, cW + 3145728, d_out, mode);
}

// Round 11
// 278.296 us; speedup vs baseline: 1.0459x; 1.0459x over previous
//
#include <hip/hip_runtime.h>
#include <hip/hip_bf16.h>
#include <cstdint>

typedef unsigned short u16;
typedef unsigned int   u32;
typedef __attribute__((ext_vector_type(8))) short short8;   // 8 bf16 (4 VGPRs) MFMA A/B frag
typedef __attribute__((ext_vector_type(4))) float f32x4;    // MFMA C/D frag / float4 load
typedef __attribute__((ext_vector_type(4))) u32  u32x4;     // 16B load/store
typedef __attribute__((ext_vector_type(2))) u32  u32x2;

#define DEV static __device__ __forceinline__

DEV float bf2f(u16 u){ u32 t = ((u32)u) << 16; float f; __builtin_memcpy(&f, &t, 4); return f; }
DEV u16 f2bf(float f){ u32 t; __builtin_memcpy(&t, &f, 4); return (u16)((t + 0x7fffu + ((t >> 16) & 1u)) >> 16); }

#if __has_builtin(__builtin_amdgcn_exp2f)
DEV float fast_exp2(float x){ return __builtin_amdgcn_exp2f(x); }
#else
DEV float fast_exp2(float x){ return exp2f(x); }
#endif

// pack hi16(x) | hi16(y)<<16  (truncation; P in [0,1])
DEV u32 pack_trunc(float x, float y){
    u32 tx, ty; __builtin_memcpy(&tx, &x, 4); __builtin_memcpy(&ty, &y, 4);
#if __has_builtin(__builtin_amdgcn_perm)
    return __builtin_amdgcn_perm(ty, tx, 0x07060302);   // bytes: [x2,x3,y2,y3]
#else
    return (tx >> 16) | (ty & 0xFFFF0000u);
#endif
}

// async global->LDS, 16B per lane. LDS dst must be wave-uniform; HW writes dst + lane*16.
DEV void gload_lds16(const void* g, void* l) {
    __builtin_amdgcn_global_load_lds((__attribute__((address_space(1))) void*)(g),
                                     (__attribute__((address_space(3))) void*)(l), 16, 0, 0);
}

// In-register quad exchange replacing the Ps LDS round-trip. (Verified in r9 bench.)
DEV short8 xchg_quads(u32 a0, u32 a1, u32 b0, u32 b1)
{
    u32 x0 = a0, y0 = b0;
    asm("v_permlane32_swap_b32 %0, %1" : "+v"(x0), "+v"(y0));
    asm("v_permlane16_swap_b32 %0, %1" : "+v"(x0), "+v"(y0));
    u32 x1 = a1, y1 = b1;
    asm("v_permlane32_swap_b32 %0, %1" : "+v"(x1), "+v"(y1));
    asm("v_permlane16_swap_b32 %0, %1" : "+v"(x1), "+v"(y1));
    union { u32 w[4]; short8 v; } u;
    u.w[0] = x0; u.w[1] = x1; u.w[2] = y0; u.w[3] = y1;
    return u.v;
}

// mode heuristic: exponent-field sanity of u16 words at even indices of x (4 KB).
DEV bool block_detect_f32(const u16* __restrict__ x, int tid, int* red)
{
    int crazy = 0;
    for (int i = tid; i < 1024; i += 256) {
        u16 v = x[2 * i];
        int e = (v >> 7) & 0xFF;
        if (e >= 0x9F || (e > 0 && e <= 0x5F)) crazy++;
    }
    #pragma unroll
    for (int off = 1; off < 64; off <<= 1) crazy += __shfl_xor(crazy, off, 64);
    if ((tid & 63) == 0) red[tid >> 6] = crazy;
    __syncthreads();
    return (red[0] + red[1] + red[2] + red[3] > 128);
}

// ---------------------------------------------------------------- canonicalize params to bf16 in ws
// r9-verified: mode detection fused per-block; weight part 8-wide vectorized.
struct SrcPtrs { const void* p[13]; };

__global__ __launch_bounds__(256) void convert_params(SrcPtrs sp, const u16* __restrict__ x,
                                                      u16* __restrict__ ws, int* __restrict__ mode)
{
    __shared__ int red[4];
    const int tid = threadIdx.x;
    const bool f = block_detect_f32(x, tid, red);
    if (blockIdx.x == 0 && tid == 0) *mode = f ? 1 : 0;

    u16* cW = ws + 33554432;
    u16* cV = ws + 37748736;
    if (blockIdx.x < 2048) {
        const int i = (blockIdx.x * 256 + tid) * 8;            // 0..4194296, 16B-aligned
        const int t = i >> 20, off = i & 1048575;
        const void* src = (t == 0) ? sp.p[6] : (t == 1) ? sp.p[8] : (t == 2) ? sp.p[10] : sp.p[12];
        if (f) {
            f32x4 a = *(const f32x4*)((const float*)src + off);
            f32x4 c = *(const f32x4*)((const float*)src + off + 4);
            u32x4 o;
            o.x = (u32)f2bf(a[0]) | ((u32)f2bf(a[1]) << 16);
            o.y = (u32)f2bf(a[2]) | ((u32)f2bf(a[3]) << 16);
            o.z = (u32)f2bf(c[0]) | ((u32)f2bf(c[1]) << 16);
            o.w = (u32)f2bf(c[2]) | ((u32)f2bf(c[3]) << 16);
            *(u32x4*)(cW + i) = o;
        } else {
            *(u32x4*)(cW + i) = *(const u32x4*)((const u16*)src + off);
        }
    } else {
        const int j = (blockIdx.x - 2048) * 256 + tid;
        if (j >= 5376) return;
        const void* src; int off;
        if      (j < 1024) { src = sp.p[0];  off = j; }
        else if (j < 2048) { src = sp.p[1];  off = j - 1024; }
        else if (j < 3072) { src = sp.p[7];  off = j - 2048; }
        else if (j < 4096) { src = sp.p[9];  off = j - 3072; }
        else if (j < 5120) { src = sp.p[11]; off = j - 4096; }
        else { int m = j - 5120; src = sp.p[2 + (m >> 6)]; off = m & 63; }
        cV[j] = f ? f2bf(((const float*)src)[off]) : ((const u16*)src)[off];
    }
}

// ---------------------------------------------------------------- LayerNorm over D=1024 (dual-mode x)
// r9-verified: one WAVE per row (64 lanes x 16 elems) — pure shuffle reduce, no LDS/syncthreads.
__global__ __launch_bounds__(256) void ln_kernel(const void* __restrict__ x,
                                                 const u16* __restrict__ w,
                                                 const u16* __restrict__ b,
                                                 u16* __restrict__ xn,
                                                 const int* __restrict__ mode)
{
    const int row  = blockIdx.x * 4 + (threadIdx.x >> 6);
    const int lane = threadIdx.x & 63;
    const int base = lane * 16;

    float v[16];
    if (*mode) {
        const float* xr = (const float*)x + (size_t)row * 1024 + base;
        #pragma unroll
        for (int c = 0; c < 4; c++) {
            f32x4 r4 = *(const f32x4*)(xr + c * 4);
            v[c*4+0] = r4[0]; v[c*4+1] = r4[1]; v[c*4+2] = r4[2]; v[c*4+3] = r4[3];
        }
    } else {
        const u16* xr = (const u16*)x + (size_t)row * 1024 + base;
        #pragma unroll
        for (int c = 0; c < 2; c++) {
            u32x4 r4 = *(const u32x4*)(xr + c * 8);
            #pragma unroll
            for (int q = 0; q < 4; q++) {
                u32 wd = (q == 0) ? r4.x : (q == 1) ? r4.y : (q == 2) ? r4.z : r4.w;
                v[c*8+q*2]   = bf2f((u16)(wd & 0xffff));
                v[c*8+q*2+1] = bf2f((u16)(wd >> 16));
            }
        }
    }
    float s = 0.0f, sq = 0.0f;
    #pragma unroll
    for (int i = 0; i < 16; i++) { s += v[i]; sq += v[i] * v[i]; }
    #pragma unroll
    for (int off = 1; off < 64; off <<= 1) {
        s  += __shfl_xor(s,  off, 64);
        sq += __shfl_xor(sq, off, 64);
    }
    const float mean = s * (1.0f / 1024.0f);
    const float var  = sq * (1.0f / 1024.0f) - mean * mean;
    const float rs   = rsqrtf(var + 1e-5f);

    #pragma unroll
    for (int c = 0; c < 2; c++) {
        u32x4 wv4 = *(const u32x4*)(w + base + c * 8);
        u32x4 bv4 = *(const u32x4*)(b + base + c * 8);
        u32x4 o;
        #pragma unroll
        for (int q = 0; q < 4; q++) {
            u32 ww = (q == 0) ? wv4.x : (q == 1) ? wv4.y : (q == 2) ? wv4.z : wv4.w;
            u32 bb = (q == 0) ? bv4.x : (q == 1) ? bv4.y : (q == 2) ? bv4.z : bv4.w;
            float y0 = (v[c*8+q*2]   - mean) * rs * bf2f((u16)(ww & 0xffff)) + bf2f((u16)(bb & 0xffff));
            float y1 = (v[c*8+q*2+1] - mean) * rs * bf2f((u16)(ww >> 16))    + bf2f((u16)(bb >> 16));
            u32 pk = (u32)f2bf(y0) | ((u32)f2bf(y1) << 16);
            if (q == 0) o.x = pk; else if (q == 1) o.y = pk; else if (q == 2) o.z = pk; else o.w = pk;
        }
        *(u32x4*)(xn + (size_t)row * 1024 + base + c * 8) = o;
    }
}

// ---------------------------------------------------------------- m97-class GEMM + XOR bank swizzle
// C = A[8192][1024] @ W[N][1024]^T. 128x128 tile, BK=64, global_load_lds(16B) staging.
// (Proven r3/r5 structure.)
__global__ __launch_bounds__(256, 4) void gemm128(const u16* __restrict__ A,
                                                  const u16* __restrict__ W,
                                                  const u16* __restrict__ bias,
                                                  void* __restrict__ out0,
                                                  u16* __restrict__ vt,
                                                  const u16* __restrict__ qnw, const u16* __restrict__ qnb,
                                                  const u16* __restrict__ knw, const u16* __restrict__ knb,
                                                  const int* __restrict__ mode,
                                                  int epi, int N)
{
    __shared__ u16 As[128 * 64];
    __shared__ u16 Bs[128 * 64];
    const int tid = threadIdx.x;
    const int m0 = blockIdx.x * 128, n0 = blockIdx.y * 128;
    const int wv = tid >> 6, lane = tid & 63, quad = lane >> 4, l16 = lane & 15;
    const int wm = wv & 1, wn = wv >> 1;

    f32x4 acc[4][4] = {};

    const int srow = tid >> 3;
    const int scol = (((tid & 7) - (srow & 7)) & 7) * 8;
    const u16* Ap = A + (size_t)(m0 + srow) * 1024 + scol;
    const u16* Wp = W + (size_t)(n0 + srow) * 1024 + scol;

    const int swz0 = ((quad     + l16) & 7) * 8;
    const int swz1 = ((quad + 4 + l16) & 7) * 8;

    for (int k0 = 0; k0 < 1024; k0 += 64) {
        #pragma unroll
        for (int i = 0; i < 4; i++)
            gload_lds16(Ap + k0 + (size_t)i * 32 * 1024, &As[i * 2048 + wv * 512]);
        #pragma unroll
        for (int i = 0; i < 4; i++)
            gload_lds16(Wp + k0 + (size_t)i * 32 * 1024, &Bs[i * 2048 + wv * 512]);
        __syncthreads();
        #pragma unroll
        for (int kh = 0; kh < 2; kh++) {
            const int sw = kh ? swz1 : swz0;
            short8 af[4], bf[4];
            #pragma unroll
            for (int mi = 0; mi < 4; mi++)
                af[mi] = *(const short8*)&As[(wm * 64 + mi * 16 + l16) * 64 + sw];
            #pragma unroll
            for (int ni = 0; ni < 4; ni++)
                bf[ni] = *(const short8*)&Bs[(wn * 64 + ni * 16 + l16) * 64 + sw];
            #pragma unroll
            for (int mi = 0; mi < 4; mi++)
                #pragma unroll
                for (int ni = 0; ni < 4; ni++)
                    acc[mi][ni] = __builtin_amdgcn_mfma_f32_16x16x32_bf16(af[mi], bf[ni], acc[mi][ni], 0, 0, 0);
        }
        __syncthreads();
    }

    if (epi == 1) {
        const int colbase = n0 + wn * 64;
        if (colbase < 2048) {
            const bool isK = colbase >= 1024;
            const u16* lw = isK ? knw : qnw;
            const u16* lb = isK ? knb : qnb;
            const float scale = isK ? 1.0f : 0.18033688011112042f;   // 0.125 * log2(e)
            float lnw[4], lnb2[4], bv[4];
            #pragma unroll
            for (int ni = 0; ni < 4; ni++) {
                const int dh = ni * 16 + l16;
                lnw[ni] = bf2f(lw[dh]); lnb2[ni] = bf2f(lb[dh]); bv[ni] = bf2f(bias[colbase + dh]);
            }
            u16* qk = (u16*)out0;
            #pragma unroll
            for (int mi = 0; mi < 4; mi++) {
                #pragma unroll
                for (int r = 0; r < 4; r++) {
                    float v[4];
                    float s = 0.0f, sq = 0.0f;
                    #pragma unroll
                    for (int ni = 0; ni < 4; ni++) {
                        v[ni] = acc[mi][ni][r] + bv[ni];
                        s += v[ni]; sq += v[ni] * v[ni];
                    }
                    #pragma unroll
                    for (int off = 1; off < 16; off <<= 1) {
                        s  += __shfl_xor(s,  off, 64);
                        sq += __shfl_xor(sq, off, 64);
                    }
                    const float mean = s * (1.0f / 64.0f);
                    const float var  = sq * (1.0f / 64.0f) - mean * mean;
                    const float rs   = rsqrtf(var + 1e-5f);
                    const int row = m0 + wm * 64 + mi * 16 + quad * 4 + r;
                    #pragma unroll
                    for (int ni = 0; ni < 4; ni++)
                        qk[(size_t)row * 2048 + colbase + ni * 16 + l16] =
                            f2bf(((v[ni] - mean) * rs * lnw[ni] + lnb2[ni]) * scale);
                }
            }
        } else {
            const int cp0 = colbase - 2048;
            #pragma unroll
            for (int ni = 0; ni < 4; ni++) {
                const int cp = cp0 + ni * 16 + l16;            // 0..1023
                const int h = cp >> 6, dh = cp & 63;
                const float bvv = bf2f(bias[2048 + cp]);
                #pragma unroll
                for (int mi = 0; mi < 4; mi++) {
                    const int row0 = m0 + wm * 64 + mi * 16 + quad * 4;
                    const int bb = row0 >> 11, nn = row0 & 2047;
                    u32x2 pk;
                    pk.x = (u32)f2bf(acc[mi][ni][0] + bvv) | ((u32)f2bf(acc[mi][ni][1] + bvv) << 16);
                    pk.y = (u32)f2bf(acc[mi][ni][2] + bvv) | ((u32)f2bf(acc[mi][ni][3] + bvv) << 16);
                    *(u32x2*)&vt[(size_t)(((bb * 16 + h) * 64) + dh) * 2048 + nn] = pk;
                }
            }
        }
    } else {
        const bool f32o = (*mode != 0);
        #pragma unroll
        for (int ni = 0; ni < 4; ni++) {
            const int col = n0 + wn * 64 + ni * 16 + l16;
            #pragma unroll
            for (int mi = 0; mi < 4; mi++) {
                const int row0 = m0 + wm * 64 + mi * 16 + quad * 4;
                #pragma unroll
                for (int r = 0; r < 4; r++) {
                    const float val = acc[mi][ni][r];
                    if (f32o) ((float*)out0)[(size_t)(row0 + r) * 1024 + col] = val;
                    else      ((u16*)out0)[(size_t)(row0 + r) * 1024 + col]  = f2bf(val);
                }
            }
        }
    }
}

// ---------------------------------------------------------------- O-projection GEMM, BM=64 x BN=128
// r13: grid (128,8) = 1024 blocks = 4 blocks/CU. (Verified r7.)
__global__ __launch_bounds__(256, 4) void gemm_o(const u16* __restrict__ A,
                                                 const u16* __restrict__ W,
                                                 void* __restrict__ out0,
                                                 const int* __restrict__ mode)
{
    __shared__ u16 As[64 * 64];
    __shared__ u16 Bs[128 * 64];
    const int tid = threadIdx.x;
    const int m0 = blockIdx.x * 64, n0 = blockIdx.y * 128;
    const int wv = tid >> 6, lane = tid & 63, quad = lane >> 4, l16 = lane & 15;

    f32x4 acc[4][2] = {};

    const int srow = tid >> 3;                               // 0..31 (wave wv covers rows wv*8..+7)
    const int scol = (((tid & 7) - (srow & 7)) & 7) * 8;
    const u16* Ap = A + (size_t)(m0 + srow) * 1024 + scol;
    const u16* Wp = W + (size_t)(n0 + srow) * 1024 + scol;

    const int swz0 = ((quad     + l16) & 7) * 8;
    const int swz1 = ((quad + 4 + l16) & 7) * 8;

    for (int k0 = 0; k0 < 1024; k0 += 64) {
        #pragma unroll
        for (int i = 0; i < 2; i++)
            gload_lds16(Ap + k0 + (size_t)i * 32 * 1024, &As[i * 2048 + wv * 512]);
        #pragma unroll
        for (int i = 0; i < 4; i++)
            gload_lds16(Wp + k0 + (size_t)i * 32 * 1024, &Bs[i * 2048 + wv * 512]);
        __syncthreads();
        #pragma unroll
        for (int kh = 0; kh < 2; kh++) {
            const int sw = kh ? swz1 : swz0;
            short8 af[4], bf[2];
            #pragma unroll
            for (int mi = 0; mi < 4; mi++)
                af[mi] = *(const short8*)&As[(mi * 16 + l16) * 64 + sw];
            #pragma unroll
            for (int ni = 0; ni < 2; ni++)
                bf[ni] = *(const short8*)&Bs[(wv * 32 + ni * 16 + l16) * 64 + sw];
            #pragma unroll
            for (int mi = 0; mi < 4; mi++)
                #pragma unroll
                for (int ni = 0; ni < 2; ni++)
                    acc[mi][ni] = __builtin_amdgcn_mfma_f32_16x16x32_bf16(af[mi], bf[ni], acc[mi][ni], 0, 0, 0);
        }
        __syncthreads();
    }

    const bool f32o = (*mode != 0);
    #pragma unroll
    for (int ni = 0; ni < 2; ni++) {
        const int col = n0 + wv * 32 + ni * 16 + l16;
        #pragma unroll
        for (int mi = 0; mi < 4; mi++) {
            const int row0 = m0 + mi * 16 + quad * 4;
            #pragma unroll
            for (int r = 0; r < 4; r++) {
                const float val = acc[mi][ni][r];
                if (f32o) ((float*)out0)[(size_t)(row0 + r) * 1024 + col] = val;
                else      ((u16*)out0)[(size_t)(row0 + r) * 1024 + col]  = f2bf(val);
            }
        }
    }
}

// ---------------------------------------------------------------- flash attention, O^T, fixed-max softmax
// r17: r9-passing attn + 4-way partial lp accumulators (breaks the 16-deep serial f32 add
//      chain per g into 4-deep partials + 2-level combine; pure reassociation, ulp-level change).
#define ATTN_STAGE(BUF) do { \
    gload_lds16(kp0, &Ks[BUF][wv * 1024]); \
    gload_lds16(kp1, &Ks[BUF][wv * 1024 + 512]); \
    gload_lds16(vp0, &Vs[BUF][wv * 1024]); \
    gload_lds16(vp1, &Vs[BUF][wv * 1024 + 512]); \
    kp0 += 64 * 2048; kp1 += 64 * 2048; vp0 += 64; vp1 += 64; } while (0)

#define ATTN_BODY(CUR, NXT, J0, DO_STAGE, DO_BAR) do { \
    if (DO_STAGE) ATTN_STAGE(NXT); \
    f32x4 sfr[2][4]; \
    _Pragma("unroll") \
    for (int sub = 0; sub < 4; sub++) { \
        short8 kf0 = *(const short8*)&Ks[CUR][krow + swz0 + sub * 1024]; \
        short8 kf1 = *(const short8*)&Ks[CUR][krow + swz1 + sub * 1024]; \
        f32x4 mrow = *(const f32x4*)&maskf[(J0) + sub * 16 + quad * 4]; \
        _Pragma("unroll") \
        for (int g = 0; g < 2; g++) { \
            f32x4 sz = mrow; \
            sz = __builtin_amdgcn_mfma_f32_16x16x32_bf16(kf0, qf[g][0], sz, 0, 0, 0); \
            sz = __builtin_amdgcn_mfma_f32_16x16x32_bf16(kf1, qf[g][1], sz, 0, 0, 0); \
            sfr[g][sub] = sz; \
        } \
    } \
    short8 pf[2][2]; \
    _Pragma("unroll") \
    for (int g = 0; g < 2; g++) { \
        f32x4 lp4 = {0.0f, 0.0f, 0.0f, 0.0f}; \
        _Pragma("unroll") \
        for (int sub = 0; sub < 4; sub++) \
            _Pragma("unroll") \
            for (int r = 0; r < 4; r++) { \
                float e = fast_exp2(sfr[g][sub][r]); \
                sfr[g][sub][r] = e; lp4[r] += e; \
            } \
        l_lane[g] += (lp4[0] + lp4[1]) + (lp4[2] + lp4[3]); \
        u32 W00 = pack_trunc(sfr[g][0][0], sfr[g][0][1]); \
        u32 W01 = pack_trunc(sfr[g][0][2], sfr[g][0][3]); \
        u32 W10 = pack_trunc(sfr[g][1][0], sfr[g][1][1]); \
        u32 W11 = pack_trunc(sfr[g][1][2], sfr[g][1][3]); \
        u32 W20 = pack_trunc(sfr[g][2][0], sfr[g][2][1]); \
        u32 W21 = pack_trunc(sfr[g][2][2], sfr[g][2][3]); \
        u32 W30 = pack_trunc(sfr[g][3][0], sfr[g][3][1]); \
        u32 W31 = pack_trunc(sfr[g][3][2], sfr[g][3][3]); \
        pf[g][0] = xchg_quads(W00, W01, W10, W11); \
        pf[g][1] = xchg_quads(W20, W21, W30, W31); \
    } \
    _Pragma("unroll") \
    for (int dht = 0; dht < 4; dht++) { \
        short8 vf0 = *(const short8*)&Vs[CUR][krow + swz0 + dht * 1024]; \
        short8 vf1 = *(const short8*)&Vs[CUR][krow + swz1 + dht * 1024]; \
        _Pragma("unroll") \
        for (int g = 0; g < 2; g++) { \
            O[g][dht] = __builtin_amdgcn_mfma_f32_16x16x32_bf16(vf0, pf[g][0], O[g][dht], 0, 0, 0); \
            O[g][dht] = __builtin_amdgcn_mfma_f32_16x16x32_bf16(vf1, pf[g][1], O[g][dht], 0, 0, 0); \
        } \
    } \
    if (DO_BAR) { \
        asm volatile("s_waitcnt vmcnt(0)" ::: "memory"); \
        __builtin_amdgcn_s_barrier(); \
    } } while (0)

__global__ __launch_bounds__(256, 4) void attn(const u16* __restrict__ qk, const u16* __restrict__ vt,
                                               const int* __restrict__ mask, u16* __restrict__ ctx)
{
    __shared__ __align__(16) float maskf[2048];     // 8 KB
    __shared__ __align__(16) u16 Ks[2][64 * 64];    // 16 KB [buf][j][dh] swizzled
    __shared__ __align__(16) u16 Vs[2][64 * 64];    // 16 KB [buf][dh][j] swizzled

    // XCD-aware remap: all 16 i-blocks of one (b,h) on one XCD (dispatch round-robin lin%8).
    const int lin = blockIdx.x;
    const int xcd = lin & 7, slot = lin >> 3;       // slot 0..127
    const int bh = (slot >> 4) * 8 + xcd;           // 0..63
    const int i0 = (slot & 15) * 128;
    const int b = bh >> 4, h = bh & 15;
    const int tid = threadIdx.x, wv = tid >> 6, lane = tid & 63, quad = lane >> 4, l16 = lane & 15;

    for (int idx = tid; idx < 2048; idx += 256)
        maskf[idx] = mask[b * 2048 + idx] ? -12.0f : -1e9f;

    const u16* qbase = qk + (size_t)(b * 2048) * 2048 + h * 64;
    const u16* kbase = qbase + 1024;
    const u16* vbase = vt + (size_t)(bh * 64) * 2048;   // rows = dh, cols = n

    short8 qf[2][2];
    #pragma unroll
    for (int g = 0; g < 2; g++) {
        const int iw = i0 + wv * 32 + g * 16 + l16;
        qf[g][0] = *(const short8*)(qbase + (size_t)iw * 2048 + quad * 8);
        qf[g][1] = *(const short8*)(qbase + (size_t)iw * 2048 + 32 + quad * 8);
    }

    f32x4 O[2][4] = {};
    float l_lane[2] = {0.0f, 0.0f};

    const int sr = lane >> 3, ss = lane & 7;
    const int sck = ((ss - sr) & 7) * 8;
    const u16* kp0 = kbase + (size_t)(wv * 16 +      sr) * 2048 + sck;
    const u16* kp1 = kbase + (size_t)(wv * 16 + 8  + sr) * 2048 + sck;
    const u16* vp0 = vbase + (size_t)(wv * 16 +      sr) * 2048 + sck;
    const u16* vp1 = vbase + (size_t)(wv * 16 + 8  + sr) * 2048 + sck;

    const int swz0 = ((quad     + l16) & 7) * 8;
    const int swz1 = ((quad + 4 + l16) & 7) * 8;
    const int krow = l16 * 64;

    ATTN_STAGE(0);
    asm volatile("s_waitcnt vmcnt(0) lgkmcnt(0)" ::: "memory");
    __builtin_amdgcn_s_barrier();

    for (int j0 = 0; j0 < 2048; j0 += 128) {
        ATTN_BODY(0, 1, j0, true, true);
        const bool more = (j0 + 128) < 2048;
        ATTN_BODY(1, 0, j0 + 64, more, more);
    }

    #pragma unroll
    for (int g = 0; g < 2; g++) {
        float l = l_lane[g];
        l += __shfl_xor(l, 16, 64);
        l += __shfl_xor(l, 32, 64);
        const float inv = l > 0.0f ? 1.0f / l : 0.0f;
        const int iw = i0 + wv * 32 + g * 16 + l16;
        u16* cb = ctx + (size_t)(b * 2048 + iw) * 1024 + h * 64;
        #pragma unroll
        for (int dht = 0; dht < 4; dht++) {
            u32x2 pk;
            pk.x = (u32)f2bf(O[g][dht][0] * inv) | ((u32)f2bf(O[g][dht][1] * inv) << 16);
            pk.y = (u32)f2bf(O[g][dht][2] * inv) | ((u32)f2bf(O[g][dht][3] * inv) << 16);
            *(u32x2*)(cb + dht * 16 + quad * 4) = pk;
        }
    }
}

// ----------------------------------------------------------------
extern "C" void kernel_launch(void* const* d_in, const int* in_sizes, int n_in,
                              void* d_out, int out_size, void* d_ws, size_t ws_size,
                              hipStream_t stream)
{
    const int* mask = (const int*)d_in[1];

    u16* ws = (u16*)d_ws;
    u16* xn  = ws;                      // [0, 8388608)
    u16* qkb = ws + 8388608;            // [8388608, 25165824)  [8192][2048]
    u16* vtb = ws + 25165824;           // [25165824, 33554432) [4][16][64][2048]
    u16* ctx = xn;                      // xn dead after QKV GEMM; reuse
    u16* cW  = ws + 33554432;           // Wq|Wk|Wv|Wo
    u16* cV  = ws + 37748736;           // vectors (5376)
    int* mode = (int*)(ws + 37754176);

    SrcPtrs sp;
    for (int i = 0; i < 13; i++) sp.p[i] = d_in[i + 2];
    convert_params<<<dim3(2069), dim3(256), 0, stream>>>(sp, (const u16*)d_in[0], ws, mode);

    ln_kernel<<<dim3(2048), dim3(256), 0, stream>>>(d_in[0], cV + 0, cV + 1024, xn, mode);

    // fused QKV + head-LN: N=3072, stacked W = cW (Wq|Wk|Wv), stacked bias = cV+2048
    gemm128<<<dim3(64, 24), dim3(256), 0, stream>>>(xn, cW, cV + 2048, qkb, vtb,
                                                    cV + 5120, cV + 5184, cV + 5248, cV + 5312,
                                                    mode, 1, 3072);

    attn<<<dim3(1024), dim3(256), 0, stream>>>(qkb, vtb, mask, ctx);

    gemm_o<<<dim3(128, 8), dim3(256), 0, stream>>>(ctx, cW + 3145728, d_out, mode);
}